// Round 11
// baseline (42.579 us; speedup 1.0000x reference)
//
#include <hip/hip_runtime.h>

// L=32768, N=32, E=H=1, BS=256 -> 4096 rank-1 softmax problems:
//   s_ij = a_i*k_j (scale=1), out_i = sum_j 2^(a'_i k_j) v_j / sum_j 2^(a'_i k_j),
//   a' = a*log2e. No max-subtraction (|arg|<=~39 log2 units, f32-safe,
//   scale-invariant; validated R5-R10).
//
// R11: LDS-return-bandwidth was the wall (98k cy/CU = 41us across R3/R8/R10:
// 4 waves/problem x 2KB broadcast reads each, ~12cy per ds_read_b128 even
// uniform). Fix: ONE wave per problem, each lane owns 4 rows (lane, +64, +128,
// +192). LDS traffic/CU drops 4x to ~24k cy; the wall becomes the issue
// stream itself: 4 problems/SIMD x 256j x (3 pk-pairs + 4 exp) ~ 55-60k cy.
// Packed v2f ops proven to select v_pk_*_f32 in R10 (busy 67k->57k).

#define LL    32768
#define NN    32
#define BSZ   256
#define NBLK  (LL / BSZ)
#define LOG2E 1.4426950408889634f

typedef float v2f __attribute__((ext_vector_type(2)));

__global__ __launch_bounds__(256) void BlockCrossAttn_kernel(
    const float* __restrict__ q_in, const float* __restrict__ k_in,
    const float* __restrict__ v_in,
    const float* __restrict__ ipw,  const float* __restrict__ ipb,
    const float* __restrict__ opw,  const float* __restrict__ opb,
    float* __restrict__ out)
{
    const int wid  = threadIdx.x >> 6;       // wave 0..3 -> one problem each
    const int lane = threadIdx.x & 63;
    const int p    = blockIdx.x * 4 + wid;   // problem id 0..4095
    const int blk  = p >> 5;                 // row-block
    const int n    = p & 31;                 // batch

    const float wq = ipw[0], wk = ipw[1], wv = ipw[2];
    const float bq = ipb[0], bk = ipb[1], bv = ipb[2];

    __shared__ alignas(16) float sk[4][BSZ];
    __shared__ alignas(16) float sv[4][BSZ];

    const int rbase = blk * BSZ;

    // Stage this wave's problem: lane owns rows lane+{0,64,128,192}.
    float a[4];
    #pragma unroll
    for (int r = 0; r < 4; ++r) {
        const int gi = (rbase + r * 64 + lane) * NN + n;
        a[r] = fmaf(q_in[gi], wq, bq) * LOG2E;
        sk[wid][r * 64 + lane] = fmaf(k_in[gi], wk, bk);
        sv[wid][r * 64 + lane] = fmaf(v_in[gi], wv, bv);
    }
    __syncthreads();

    const v2f a01 = {a[0], a[1]};
    const v2f a23 = {a[2], a[3]};

    // even/odd accumulator split: each chain updated every 2nd j
    v2f d01e = {0.f, 0.f}, d01o = {0.f, 0.f}, d23e = {0.f, 0.f}, d23o = {0.f, 0.f};
    v2f n01e = {0.f, 0.f}, n01o = {0.f, 0.f}, n23e = {0.f, 0.f}, n23o = {0.f, 0.f};

    const float4* __restrict__ k4p = (const float4*)sk[wid];
    const float4* __restrict__ v4p = (const float4*)sv[wid];

    #pragma unroll 8
    for (int t = 0; t < BSZ / 4; ++t) {
        const float4 k4 = k4p[t];      // uniform ds_read_b128 (broadcast)
        const float4 v4 = v4p[t];

        {   // j0 (even)
            const v2f arg0 = a01 * (v2f){k4.x, k4.x};
            const v2f arg1 = a23 * (v2f){k4.x, k4.x};
            v2f p0, p1;
            p0.x = __builtin_amdgcn_exp2f(arg0.x);
            p0.y = __builtin_amdgcn_exp2f(arg0.y);
            p1.x = __builtin_amdgcn_exp2f(arg1.x);
            p1.y = __builtin_amdgcn_exp2f(arg1.y);
            d01e += p0; d23e += p1;
            n01e = __builtin_elementwise_fma(p0, (v2f){v4.x, v4.x}, n01e);
            n23e = __builtin_elementwise_fma(p1, (v2f){v4.x, v4.x}, n23e);
        }
        {   // j1 (odd)
            const v2f arg0 = a01 * (v2f){k4.y, k4.y};
            const v2f arg1 = a23 * (v2f){k4.y, k4.y};
            v2f p0, p1;
            p0.x = __builtin_amdgcn_exp2f(arg0.x);
            p0.y = __builtin_amdgcn_exp2f(arg0.y);
            p1.x = __builtin_amdgcn_exp2f(arg1.x);
            p1.y = __builtin_amdgcn_exp2f(arg1.y);
            d01o += p0; d23o += p1;
            n01o = __builtin_elementwise_fma(p0, (v2f){v4.y, v4.y}, n01o);
            n23o = __builtin_elementwise_fma(p1, (v2f){v4.y, v4.y}, n23o);
        }
        {   // j2 (even)
            const v2f arg0 = a01 * (v2f){k4.z, k4.z};
            const v2f arg1 = a23 * (v2f){k4.z, k4.z};
            v2f p0, p1;
            p0.x = __builtin_amdgcn_exp2f(arg0.x);
            p0.y = __builtin_amdgcn_exp2f(arg0.y);
            p1.x = __builtin_amdgcn_exp2f(arg1.x);
            p1.y = __builtin_amdgcn_exp2f(arg1.y);
            d01e += p0; d23e += p1;
            n01e = __builtin_elementwise_fma(p0, (v2f){v4.z, v4.z}, n01e);
            n23e = __builtin_elementwise_fma(p1, (v2f){v4.z, v4.z}, n23e);
        }
        {   // j3 (odd)
            const v2f arg0 = a01 * (v2f){k4.w, k4.w};
            const v2f arg1 = a23 * (v2f){k4.w, k4.w};
            v2f p0, p1;
            p0.x = __builtin_amdgcn_exp2f(arg0.x);
            p0.y = __builtin_amdgcn_exp2f(arg0.y);
            p1.x = __builtin_amdgcn_exp2f(arg1.x);
            p1.y = __builtin_amdgcn_exp2f(arg1.y);
            d01o += p0; d23o += p1;
            n01o = __builtin_elementwise_fma(p0, (v2f){v4.w, v4.w}, n01o);
            n23o = __builtin_elementwise_fma(p1, (v2f){v4.w, v4.w}, n23o);
        }
    }

    const v2f d01 = d01e + d01o, d23 = d23e + d23o;
    const v2f n01 = n01e + n01o, n23 = n23e + n23o;

    const float wo = opw[0], bo = opb[0];
    out[(size_t)(rbase +   0 + lane) * NN + n] = fmaf(n01.x / d01.x, wo, bo);
    out[(size_t)(rbase +  64 + lane) * NN + n] = fmaf(n01.y / d01.y, wo, bo);
    out[(size_t)(rbase + 128 + lane) * NN + n] = fmaf(n23.x / d23.x, wo, bo);
    out[(size_t)(rbase + 192 + lane) * NN + n] = fmaf(n23.y / d23.y, wo, bo);
}

extern "C" void kernel_launch(void* const* d_in, const int* in_sizes, int n_in,
                              void* d_out, int out_size, void* d_ws, size_t ws_size,
                              hipStream_t stream) {
    const float* q   = (const float*)d_in[0];
    const float* k   = (const float*)d_in[1];
    const float* v   = (const float*)d_in[2];
    const float* ipw = (const float*)d_in[3];
    const float* ipb = (const float*)d_in[4];
    const float* opw = (const float*)d_in[5];
    const float* opb = (const float*)d_in[6];
    float* out = (float*)d_out;

    dim3 grid(NBLK * NN / 4);   // 1024 WGs x 4 waves; one problem per wave
    dim3 block(256);
    BlockCrossAttn_kernel<<<grid, block, 0, stream>>>(q, k, v, ipw, ipb, opw, opb, out);
}